// Round 10
// baseline (331.062 us; speedup 1.0000x reference)
//
#include <hip/hip_runtime.h>
#include <math.h>

#define N_PTS 16384
#define K_NBR 16
#define H_DIM 64
#define TS    1024   // kNN LDS tile (points)
#define CAP   160    // per-row candidate buffer (entries, kept even)

typedef unsigned long long u64;
typedef float v2f __attribute__((ext_vector_type(2)));
typedef float v4f __attribute__((ext_vector_type(4)));

// prefix count of set bits of m strictly below my lane
__device__ __forceinline__ int prefix_lt(u64 m) {
    return __builtin_amdgcn_mbcnt_hi((unsigned)(m >> 32),
           __builtin_amdgcn_mbcnt_lo((unsigned)m, 0));
}
// key = (order-preserving float bits, ~idx): sorts by value desc then idx asc
__device__ __forceinline__ u64 mkkey(unsigned vbits, unsigned idx) {
    unsigned of = vbits ^ (unsigned)(((int)vbits >> 31) | 0x80000000);
    return ((u64)of << 32) | (unsigned)(~idx);
}
__device__ __forceinline__ unsigned keyidx(u64 k) { return ~(unsigned)k; }

__device__ __forceinline__ float readlane_f(float v, int l) {
    return __uint_as_float(__builtin_amdgcn_readlane(__float_as_uint(v), l));
}

// 64-lane bitonic ascending sort, float
__device__ __forceinline__ float wave_sort_f32(float v, int lane) {
#pragma unroll
    for (int k = 2; k <= 64; k <<= 1) {
#pragma unroll
        for (int j = k >> 1; j > 0; j >>= 1) {
            float o = __shfl_xor(v, j, 64);
            bool keep_min = (((lane & k) == 0) == ((lane & j) == 0));
            v = keep_min ? fminf(v, o) : fmaxf(v, o);
        }
    }
    return v;
}
// 64-lane bitonic ascending sort, u64 keys
__device__ __forceinline__ u64 wave_sort_u64(u64 v, int lane) {
#pragma unroll
    for (int k = 2; k <= 64; k <<= 1) {
#pragma unroll
        for (int j = k >> 1; j > 0; j >>= 1) {
            u64 o = __shfl_xor((unsigned long long)v, j, 64);
            bool keep_min = (((lane & k) == 0) == ((lane & j) == 0));
            u64 mn = (v < o) ? v : o;
            u64 mx = (v < o) ? o : v;
            v = keep_min ? mn : mx;
        }
    }
    return v;
}

// raise tau to 16th-largest of per-lane max VALUES, drop entries below.
// Exact: tau <= 16th-largest value seen; >=-keep retains all boundary ties.
__device__ __forceinline__ int wave_compact(uint2* buf, int cnt, float* tau,
                                            int lane) {
    float lm = -INFINITY;
    for (int s = lane; s < cnt; s += 64)
        lm = fmaxf(lm, __uint_as_float(buf[s].x));
    const float tv = readlane_f(wave_sort_f32(lm, lane), 48);
    int nc = 0;
    for (int s0 = 0; s0 < cnt; s0 += 64) {
        const int s = s0 + lane;
        uint2 e = make_uint2(0u, 0u);
        bool keep = false;
        if (s < cnt) { e = buf[s]; keep = (__uint_as_float(e.x) >= tv); }
        const u64 km = __ballot(keep);
        if (keep) buf[nc + prefix_lt(km)] = e;  // write idx <= read idx: safe
        nc += (int)__popcll(km);
    }
    *tau = tv;
    return nc;
}

// ---------------- xx[i] = sum(x[i]^2), mimicking numpy squares-then-sum ----
__global__ __launch_bounds__(256) void xx_kernel(const float4* __restrict__ x4,
                                                 float* __restrict__ xx) {
    int i = blockIdx.x * 256 + threadIdx.x;
    float4 v = x4[i];
    {
#pragma clang fp contract(off)
        float s0 = v.x * v.x;
        float s1 = v.y * v.y;
        float s2 = v.z * v.z;
        float s3 = v.w * v.w;
        xx[i] = ((s0 + s1) + s2) + s3;
    }
}

// ---------------- brute-force kNN: 2 rows/wave, b128 candidate QUADS -------
// x staged component-transposed; ds_read_b128 yields 4 candidates pre-packed
// for v_pk_fma_f32. Register-prefetch hides staging global latency across the
// processing phase. Event path appends the whole quad (2 aligned b128 writes);
// sub-tau components are legit small candidates, dropped at compaction.
__global__ __launch_bounds__(256, 5) void knn_kernel(
        const float4* __restrict__ x4,
        const float* __restrict__ xx,
        int* __restrict__ knn) {
    __shared__ __align__(16) float xsc[4][TS];   // 16 KB, component-transposed
    __shared__ __align__(16) float nxxs[TS];     // 4 KB
    __shared__ __align__(16) uint2 buf[8][CAP];  // 10 KB  (30 KB -> 5 blk/CU)
    const int lane = threadIdx.x & 63;
    const int wave = threadIdx.x >> 6;
    const int row0 = blockIdx.x * 8 + wave * 2;
    const float4* xxf4 = (const float4*)xx;

    float4 y[2]; float nxxi[2]; uint2* bufr[2];
#pragma unroll
    for (int r = 0; r < 2; ++r) {
        const float4 t0 = x4[row0 + r];
        y[r] = make_float4(2.0f * t0.x, 2.0f * t0.y, 2.0f * t0.z, 2.0f * t0.w);
        nxxi[r] = -xx[row0 + r];
        bufr[r] = &buf[wave * 2 + r][0];
    }
    float tau[2]; int cnt[2];

    auto quad_p = [&](int e, int r) -> v4f {     // 4 candidates at local e
        const v4f ax  = *(const v4f*)&xsc[0][e];
        const v4f ay  = *(const v4f*)&xsc[1][e];
        const v4f az  = *(const v4f*)&xsc[2][e];
        const v4f aw  = *(const v4f*)&xsc[3][e];
        const v4f nx4 = *(const v4f*)&nxxs[e];
        v4f acc = nx4 + (v4f){nxxi[r], nxxi[r], nxxi[r], nxxi[r]};
        acc = __builtin_elementwise_fma(ax, (v4f){y[r].x,y[r].x,y[r].x,y[r].x}, acc);
        acc = __builtin_elementwise_fma(ay, (v4f){y[r].y,y[r].y,y[r].y,y[r].y}, acc);
        acc = __builtin_elementwise_fma(az, (v4f){y[r].z,y[r].z,y[r].z,y[r].z}, acc);
        acc = __builtin_elementwise_fma(aw, (v4f){y[r].w,y[r].w,y[r].w,y[r].w}, acc);
        return acc;
    };
    auto pad_even = [&](int r) {                 // keep cnt even (b128 align)
        if (cnt[r] & 1) {
            if (lane == 0)
                bufr[r][cnt[r]] = make_uint2(0xff800000u, 0xffffffffu); // -inf
            cnt[r]++;
        }
    };

    // prefetch tile 0 (4 consecutive points per thread, transposed at write)
    float4 prex[4]; float4 prexx;
#pragma unroll
    for (int j = 0; j < 4; ++j) prex[j] = x4[4 * threadIdx.x + j];
    prexx = xxf4[threadIdx.x];

    for (int t = 0; t < N_PTS / TS; ++t) {
        __syncthreads();                          // prev tile fully processed
        {
            const int i = 4 * threadIdx.x;
            *(v4f*)&xsc[0][i] = (v4f){prex[0].x, prex[1].x, prex[2].x, prex[3].x};
            *(v4f*)&xsc[1][i] = (v4f){prex[0].y, prex[1].y, prex[2].y, prex[3].y};
            *(v4f*)&xsc[2][i] = (v4f){prex[0].z, prex[1].z, prex[2].z, prex[3].z};
            *(v4f*)&xsc[3][i] = (v4f){prex[0].w, prex[1].w, prex[2].w, prex[3].w};
            *(v4f*)&nxxs[i]   = (v4f){-prexx.x, -prexx.y, -prexx.z, -prexx.w};
        }
        __syncthreads();
        if (t + 1 < N_PTS / TS) {                 // prefetch next tile; loads
            const int pbase = (t + 1) * TS;       // complete during processing
#pragma unroll
            for (int j = 0; j < 4; ++j)
                prex[j] = x4[pbase + 4 * threadIdx.x + j];
            prexx = xxf4[pbase / 4 + threadIdx.x];
        }

        int jq0 = 0;
        if (t == 0) {
            // seed: tau = 16th-largest of 64 quad-maxima over first 256 cands
            // (the top-16 maxima are 16 distinct candidates >= m16 -> safe);
            // >=-append keeps every possibly-needed entry (<=64 non-degenerate)
            const int e = 4 * lane;
#pragma unroll
            for (int r = 0; r < 2; ++r) {
                const v4f P = quad_p(e, r);
                const float mx = fmaxf(fmaxf(P.x, P.y), fmaxf(P.z, P.w));
                tau[r] = readlane_f(wave_sort_f32(mx, lane), 48);
                const u64 m0 = __ballot(P.x >= tau[r]);
                const u64 m1 = __ballot(P.y >= tau[r]);
                const u64 m2 = __ballot(P.z >= tau[r]);
                const u64 m3 = __ballot(P.w >= tau[r]);
                const int c0 = (int)__popcll(m0);
                const int c1 = c0 + (int)__popcll(m1);
                const int c2 = c1 + (int)__popcll(m2);
                if (P.x >= tau[r]) bufr[r][prefix_lt(m0)] =
                    make_uint2(__float_as_uint(P.x), (unsigned)(e + 0));
                if (P.y >= tau[r]) bufr[r][c0 + prefix_lt(m1)] =
                    make_uint2(__float_as_uint(P.y), (unsigned)(e + 1));
                if (P.z >= tau[r]) bufr[r][c1 + prefix_lt(m2)] =
                    make_uint2(__float_as_uint(P.z), (unsigned)(e + 2));
                if (P.w >= tau[r]) bufr[r][c2 + prefix_lt(m3)] =
                    make_uint2(__float_as_uint(P.w), (unsigned)(e + 3));
                cnt[r] = c2 + (int)__popcll(m3);
                pad_even(r);
            }
            jq0 = 1;
        }

        for (int jq = jq0; jq < TS / 256; ++jq) {
            const int off = jq * 256;
            const int e = off + 4 * lane;
            const int cb = t * TS + e;            // global idx of candidate 0
            v4f P[2]; float mx[2]; u64 m[2];
#pragma unroll
            for (int r = 0; r < 2; ++r) {
                P[r] = quad_p(e, r);
                mx[r] = fmaxf(fmaxf(P[r].x, P[r].y), fmaxf(P[r].z, P[r].w));
                m[r] = __ballot(mx[r] > tau[r]);
            }
            if (m[0] | m[1]) {                    // wave-uniform, rare
#pragma unroll
                for (int r = 0; r < 2; ++r) {
                    if (m[r]) {
                        int add = 4 * (int)__popcll(m[r]);
                        if (cnt[r] + add > CAP) {
                            cnt[r] = wave_compact(bufr[r], cnt[r], &tau[r], lane);
                            pad_even(r);
                            m[r] = __ballot(mx[r] > tau[r]);
                            add = 4 * (int)__popcll(m[r]);
                        }
                        if (cnt[r] + add <= CAP) {   // fast quad-append
                            if (mx[r] > tau[r]) {
                                const int slot = cnt[r] + 4 * prefix_lt(m[r]);
                                uint4 w0 = make_uint4(
                                    __float_as_uint(P[r].x), (unsigned)(cb + 0),
                                    __float_as_uint(P[r].y), (unsigned)(cb + 1));
                                uint4 w1 = make_uint4(
                                    __float_as_uint(P[r].z), (unsigned)(cb + 2),
                                    __float_as_uint(P[r].w), (unsigned)(cb + 3));
                                *reinterpret_cast<uint4*>(&bufr[r][slot])     = w0;
                                *reinterpret_cast<uint4*>(&bufr[r][slot + 2]) = w1;
                            }
                            cnt[r] += add;
                        } else {                     // ~never: component append
                            const u64 ma = __ballot(P[r].x > tau[r]);
                            const u64 mb = __ballot(P[r].y > tau[r]);
                            const u64 mc = __ballot(P[r].z > tau[r]);
                            const u64 md = __ballot(P[r].w > tau[r]);
                            const int ca = (int)__popcll(ma);
                            const int cbn = ca + (int)__popcll(mb);
                            const int cc = cbn + (int)__popcll(mc);
                            if (P[r].x > tau[r]) bufr[r][cnt[r] + prefix_lt(ma)] =
                                make_uint2(__float_as_uint(P[r].x), (unsigned)(cb + 0));
                            if (P[r].y > tau[r]) bufr[r][cnt[r] + ca + prefix_lt(mb)] =
                                make_uint2(__float_as_uint(P[r].y), (unsigned)(cb + 1));
                            if (P[r].z > tau[r]) bufr[r][cnt[r] + cbn + prefix_lt(mc)] =
                                make_uint2(__float_as_uint(P[r].z), (unsigned)(cb + 2));
                            if (P[r].w > tau[r]) bufr[r][cnt[r] + cc + prefix_lt(md)] =
                                make_uint2(__float_as_uint(P[r].w), (unsigned)(cb + 3));
                            cnt[r] += cc + (int)__popcll(md);
                            pad_even(r);
                        }
                    }
                }
            }
        }
    }

    // final: compact (<=48), one u64-key bitonic sort, lanes 48..63 = top-16
#pragma unroll
    for (int r = 0; r < 2; ++r) {
        const int c2 = wave_compact(bufr[r], cnt[r], &tau[r], lane);
        u64 key = 0;                               // sentinel < any real key
        if (lane < c2) {
            const uint2 e = bufr[r][lane];
            key = mkkey(e.x, e.y);
        }
        key = wave_sort_u64(key, lane);
        if (lane >= 48)
            knn[(row0 + r) * K_NBR + (lane - 48)] = (int)keyidx(key);
    }
}

// ---------------- edge-feature MLP: h4-outer, W2 from L2, pk-fp32 ----------
// Layer1: lane = hidden h for both points (rows pp*16+k, stride 68: 2-way ok).
// Layer2: lane (kq=lane>>4, gp=lane&15); h4-outer so each W2 fragment is
// loaded once per h4 (global, L2-hot) and reused across 2 points x 4 kk.
__global__ __launch_bounds__(256, 4) void mlp_kernel(
        const float4* __restrict__ x4,
        const int* __restrict__ knn,
        const float4* __restrict__ W2f4,
        const float* __restrict__ W1,
        const float* __restrict__ b1,
        const float* __restrict__ b2,
        float* __restrict__ out) {
    __shared__ __align__(16) float h1s[4][32][68];   // 34 KB -> 4 blk/CU
    const int lane = threadIdx.x & 63;
    const int wave = threadIdx.x >> 6;
    const int kq   = lane >> 4;
    const int gp   = lane & 15;
    const int p0   = (blockIdx.x * 4 + wave) * 2;    // 2 points per wave

    float w1r[8];
#pragma unroll
    for (int c = 0; c < 8; ++c) w1r[c] = W1[lane * 8 + c];
    const float b1r = b1[lane];
    float b2r[4];
#pragma unroll
    for (int gq = 0; gq < 4; ++gq) b2r[gq] = b2[gq * 16 + gp];

    // layer 1 for both points (lane = hidden feature h)
#pragma unroll
    for (int pp = 0; pp < 2; ++pp) {
        const int p = p0 + pp;
        const float4 xi = x4[p];
        for (int k = 0; k < K_NBR; ++k) {
            const int nb = knn[p * K_NBR + k];
            const float4 xj = x4[nb];
            float h = b1r;
            h = fmaf(w1r[0], xj.x - xi.x, h);
            h = fmaf(w1r[1], xj.y - xi.y, h);
            h = fmaf(w1r[2], xj.z - xi.z, h);
            h = fmaf(w1r[3], xj.w - xi.w, h);
            h = fmaf(w1r[4], xi.x, h);
            h = fmaf(w1r[5], xi.y, h);
            h = fmaf(w1r[6], xi.z, h);
            h = fmaf(w1r[7], xi.w, h);
            h1s[wave][pp * 16 + k][lane] = fmaxf(h, 0.0f);
        }
    }
    // wave-private LDS slice: in-wave lgkmcnt ordering suffices, no barrier

    // layer 2: acc[pp][kk][gq] packed pairs over h
    v2f acc[2][4][4];
#pragma unroll
    for (int pp = 0; pp < 2; ++pp)
#pragma unroll
        for (int kk = 0; kk < 4; ++kk)
#pragma unroll
            for (int gq = 0; gq < 4; ++gq)
                acc[pp][kk][gq] = (v2f){b2r[gq], 0.0f};

#pragma unroll
    for (int h4 = 0; h4 < 16; ++h4) {
        float4 w4[4];
#pragma unroll
        for (int gq = 0; gq < 4; ++gq)
            w4[gq] = W2f4[(gq * 16 + gp) * 16 + h4];   // global, L2-hot
#pragma unroll
        for (int pp = 0; pp < 2; ++pp) {
#pragma unroll
            for (int kk = 0; kk < 4; ++kk) {
                const float4 hv =
                    *(const float4*)&h1s[wave][pp * 16 + kq * 4 + kk][h4 * 4];
#pragma unroll
                for (int gq = 0; gq < 4; ++gq) {
                    acc[pp][kk][gq] = __builtin_elementwise_fma(
                        (v2f){hv.x, hv.y}, (v2f){w4[gq].x, w4[gq].y},
                        acc[pp][kk][gq]);
                    acc[pp][kk][gq] = __builtin_elementwise_fma(
                        (v2f){hv.z, hv.w}, (v2f){w4[gq].z, w4[gq].w},
                        acc[pp][kk][gq]);
                }
            }
        }
    }

#pragma unroll
    for (int pp = 0; pp < 2; ++pp) {
        float s[4];
#pragma unroll
        for (int gq = 0; gq < 4; ++gq) {
            s[gq] = 0.0f;
#pragma unroll
            for (int kk = 0; kk < 4; ++kk) {
                const float v = acc[pp][kk][gq].x + acc[pp][kk][gq].y;
                s[gq] += fmaxf(v, 0.0f);
            }
        }
#pragma unroll
        for (int off = 16; off <= 32; off <<= 1)
#pragma unroll
            for (int gq = 0; gq < 4; ++gq)
                s[gq] += __shfl_xor(s[gq], off, 64);

        out[(p0 + pp) * H_DIM + kq * 16 + gp] = s[kq] * (1.0f / 16.0f);
    }
}

extern "C" void kernel_launch(void* const* d_in, const int* in_sizes, int n_in,
                              void* d_out, int out_size, void* d_ws, size_t ws_size,
                              hipStream_t stream) {
    (void)in_sizes; (void)n_in; (void)out_size; (void)ws_size;
    const float* x  = (const float*)d_in[0];
    const float* W1 = (const float*)d_in[1];
    const float* b1 = (const float*)d_in[2];
    const float* W2 = (const float*)d_in[3];
    const float* b2 = (const float*)d_in[4];
    float* out = (float*)d_out;

    float* xx  = (float*)d_ws;                                  // N floats
    int*   knn = (int*)((char*)d_ws + N_PTS * sizeof(float));   // N*K ints

    const float4* x4 = (const float4*)x;

    xx_kernel <<<N_PTS / 256, 256, 0, stream>>>(x4, xx);
    knn_kernel<<<N_PTS / 8,   256, 0, stream>>>(x4, xx, knn);
    mlp_kernel<<<N_PTS / 8,   256, 0, stream>>>(
        x4, knn, (const float4*)W2, W1, b1, b2, out);
}